// Round 1
// baseline (335.156 us; speedup 1.0000x reference)
//
#include <hip/hip_runtime.h>
#include <math.h>

#define TX 64          // output cols per block
#define TY 32          // output rows per block
#define TXH 74         // TX + 10 (halo cols)
#define TXP 76         // padded LDS row stride (multiple of 4 for float4)
#define NTHREADS 256

constexpr int H = 512, W = 512;
constexpr int NPLANES = 96;            // 32 * 3
constexpr double NTOT = 25165824.0;    // 32*3*512*512
constexpr float C1 = 1.0e-4f;          // (0.01*1)^2
constexpr float C2 = 9.0e-4f;          // (0.03*1)^2

struct Wts { float w[11]; };

// Phase 1: vertical 11-tap conv of {x1,x2,x1^2,x2^2,x1x2} from global -> LDS.
// Row-paired: two consecutive vb rows share 12 tap loads + product computation.
template<bool EDGE>
__device__ __forceinline__ void phase1(const float* __restrict__ p1,
                                       const float* __restrict__ p2,
                                       float (&vb)[5][TY][TXP],
                                       int tx0, int ty0, const Wts& wts, int tid)
{
    for (int i = tid; i < (TY / 2) * TXH; i += NTHREADS) {
        const int rh = i / TXH;
        const int c  = i - rh * TXH;
        const int r  = rh * 2;
        const int x  = tx0 - 5 + c;
        const int yb = ty0 - 5 + r;
        const bool xin = (x >= 0) && (x < W);

        float m1a = 0.f, m2a = 0.f, q11a = 0.f, q22a = 0.f, q12a = 0.f;
        float m1b = 0.f, m2b = 0.f, q11b = 0.f, q22b = 0.f, q12b = 0.f;

        #pragma unroll
        for (int k = 0; k < 12; ++k) {
            const int y = yb + k;
            float v1 = 0.f, v2 = 0.f;
            if (EDGE) {
                const bool ok = xin && (y >= 0) && (y < H);
                if (ok) { v1 = p1[y * W + x]; v2 = p2[y * W + x]; }
            } else {
                v1 = p1[y * W + x];
                v2 = p2[y * W + x];
            }
            const float p11 = v1 * v1, p22 = v2 * v2, p12 = v1 * v2;
            if (k < 11) {
                const float wk = wts.w[k];
                m1a += wk * v1;  m2a += wk * v2;
                q11a += wk * p11; q22a += wk * p22; q12a += wk * p12;
            }
            if (k >= 1) {
                const float wk = wts.w[k - 1];
                m1b += wk * v1;  m2b += wk * v2;
                q11b += wk * p11; q22b += wk * p22; q12b += wk * p12;
            }
        }
        vb[0][r][c] = m1a;  vb[1][r][c] = m2a;
        vb[2][r][c] = q11a; vb[3][r][c] = q22a; vb[4][r][c] = q12a;
        vb[0][r + 1][c] = m1b;  vb[1][r + 1][c] = m2b;
        vb[2][r + 1][c] = q11b; vb[3][r + 1][c] = q22b; vb[4][r + 1][c] = q12b;
    }
}

__global__ __launch_bounds__(NTHREADS)
void ssim_main_kernel(const float* __restrict__ img1, const float* __restrict__ img2,
                      double* __restrict__ acc, Wts wts)
{
    __shared__ float vb[5][TY][TXP];
    __shared__ float red[NTHREADS / 64];

    const int tid = threadIdx.x;
    const int tx0 = blockIdx.x * TX;
    const int ty0 = blockIdx.y * TY;
    const long plane = (long)blockIdx.z * (H * W);
    const float* p1 = img1 + plane;
    const float* p2 = img2 + plane;

    const bool edge = (blockIdx.x == 0) || (blockIdx.x == gridDim.x - 1) ||
                      (blockIdx.y == 0) || (blockIdx.y == gridDim.y - 1);
    if (edge) phase1<true>(p1, p2, vb, tx0, ty0, wts, tid);
    else      phase1<false>(p1, p2, vb, tx0, ty0, wts, tid);

    __syncthreads();

    // Phase 2: horizontal 11-tap conv (register window via aligned float4 LDS
    // reads) + SSIM map. Each thread: 4 consecutive cols x 2 rows.
    const int cg = tid & 15;   // col group: cols 4*cg .. 4*cg+3
    const int rg = tid >> 4;   // row group: rows 2*rg, 2*rg+1
    const int c0 = cg * 4;

    float local = 0.f;
    #pragma unroll
    for (int rr = 0; rr < 2; ++rr) {
        const int r = rg * 2 + rr;
        float acc5[5][4];
        #pragma unroll
        for (int ch = 0; ch < 5; ++ch) {
            float f[16];
            #pragma unroll
            for (int j = 0; j < 4; ++j) {
                const float4 v = *(const float4*)&vb[ch][r][c0 + 4 * j];
                f[4 * j + 0] = v.x; f[4 * j + 1] = v.y;
                f[4 * j + 2] = v.z; f[4 * j + 3] = v.w;
            }
            #pragma unroll
            for (int j = 0; j < 4; ++j) {
                float s = 0.f;
                #pragma unroll
                for (int k = 0; k < 11; ++k) s += wts.w[k] * f[j + k];
                acc5[ch][j] = s;
            }
        }
        #pragma unroll
        for (int j = 0; j < 4; ++j) {
            const float m1 = acc5[0][j], m2 = acc5[1][j];
            const float mu11 = m1 * m1, mu22 = m2 * m2, mu12 = m1 * m2;
            const float sg1  = acc5[2][j] - mu11;
            const float sg2  = acc5[3][j] - mu22;
            const float sg12 = acc5[4][j] - mu12;
            const float num = (2.f * mu12 + C1) * (2.f * sg12 + C2);
            const float den = (mu11 + mu22 + C1) * (sg1 + sg2 + C2);
            local += num / den;
        }
    }

    // Block reduction: wave shuffle -> LDS -> one double atomic per block.
    #pragma unroll
    for (int off = 32; off > 0; off >>= 1) local += __shfl_down(local, off, 64);
    if ((tid & 63) == 0) red[tid >> 6] = local;
    __syncthreads();
    if (tid == 0) {
        float s = 0.f;
        #pragma unroll
        for (int wv = 0; wv < NTHREADS / 64; ++wv) s += red[wv];
        atomicAdd(acc, (double)s);
    }
}

__global__ void ssim_final_kernel(const double* __restrict__ acc, float* __restrict__ out)
{
    out[0] = 1.0f - (float)(acc[0] / NTOT);
}

extern "C" void kernel_launch(void* const* d_in, const int* in_sizes, int n_in,
                              void* d_out, int out_size, void* d_ws, size_t ws_size,
                              hipStream_t stream)
{
    const float* img1 = (const float*)d_in[0];
    const float* img2 = (const float*)d_in[1];
    float* out = (float*)d_out;
    double* acc = (double*)d_ws;

    hipMemsetAsync(d_ws, 0, sizeof(double), stream);

    Wts wts;
    double wd[11], s = 0.0;
    for (int k = 0; k < 11; ++k) {
        const double d = (double)(k - 5);
        wd[k] = exp(-0.5 / (1.5 * 1.5) * d * d);
        s += wd[k];
    }
    for (int k = 0; k < 11; ++k) wts.w[k] = (float)(wd[k] / s);

    dim3 grid(W / TX, H / TY, NPLANES);
    ssim_main_kernel<<<grid, NTHREADS, 0, stream>>>(img1, img2, acc, wts);
    ssim_final_kernel<<<1, 1, 0, stream>>>(acc, out);
}

// Round 2
// 271.001 us; speedup vs baseline: 1.2367x; 1.2367x over previous
//
#include <hip/hip_runtime.h>
#include <math.h>

#define TX 128         // output cols per block
#define TY 32          // output rows per block
#define TXH 138        // TX + 10 halo cols
#define TXP 148        // LDS row stride in floats: 37 chunks of 16B, 37 odd & coprime w/ 32 banks
#define NTHREADS 512

constexpr int H = 512, W = 512;
constexpr int NPLANES = 96;             // 32 * 3
constexpr int GX = W / TX;              // 4
constexpr int GY = H / TY;              // 16
constexpr int NB = GX * GY * NPLANES;   // 6144 blocks
constexpr double NTOT = 25165824.0;     // 32*3*512*512
constexpr float C1 = 1.0e-4f;           // (0.01*1)^2
constexpr float C2 = 9.0e-4f;           // (0.03*1)^2

struct Wts { float w[11]; };

// Phase 1: vertical 11-tap conv of {a, b, a^2, b^2} (a=x1+x2, b=x1-x2),
// global -> LDS. 4 output rows share 14 tap loads + one product set.
template<bool EDGE>
__device__ __forceinline__ void phase1(const float* __restrict__ p1,
                                       const float* __restrict__ p2,
                                       float (&vb)[4][TY][TXP],
                                       int tx0, int ty0, const Wts& wts, int tid)
{
    for (int i = tid; i < (TY / 4) * TXH; i += NTHREADS) {
        const int rh = i / TXH;          // 0..7  (4-row group)
        const int c  = i - rh * TXH;     // 0..137 (halo col)
        const int x  = tx0 - 5 + c;
        const int yb = ty0 - 5 + 4 * rh;
        const bool xin = (x >= 0) && (x < W);

        float aA[4]  = {0.f, 0.f, 0.f, 0.f};
        float aB[4]  = {0.f, 0.f, 0.f, 0.f};
        float aQa[4] = {0.f, 0.f, 0.f, 0.f};
        float aQb[4] = {0.f, 0.f, 0.f, 0.f};

        #pragma unroll
        for (int t = 0; t < 14; ++t) {
            const int y = yb + t;
            float v1 = 0.f, v2 = 0.f;
            if (EDGE) {
                if (xin && (y >= 0) && (y < H)) {
                    v1 = p1[y * W + x];
                    v2 = p2[y * W + x];
                }
            } else {
                v1 = p1[y * W + x];
                v2 = p2[y * W + x];
            }
            const float av = v1 + v2, bv = v1 - v2;
            const float a2 = av * av, b2 = bv * bv;
            #pragma unroll
            for (int d = 0; d < 4; ++d) {
                const int k = t - d;
                if (k >= 0 && k <= 10) {
                    const float wk = wts.w[k];
                    aA[d]  = fmaf(wk, av, aA[d]);
                    aB[d]  = fmaf(wk, bv, aB[d]);
                    aQa[d] = fmaf(wk, a2, aQa[d]);
                    aQb[d] = fmaf(wk, b2, aQb[d]);
                }
            }
        }
        #pragma unroll
        for (int d = 0; d < 4; ++d) {
            const int r = 4 * rh + d;
            vb[0][r][c] = aA[d];
            vb[1][r][c] = aB[d];
            vb[2][r][c] = aQa[d];
            vb[3][r][c] = aQb[d];
        }
    }
}

__global__ __launch_bounds__(NTHREADS, 4)
void ssim_main_kernel(const float* __restrict__ img1, const float* __restrict__ img2,
                      float* __restrict__ part, Wts wts)
{
    __shared__ float vb[4][TY][TXP];     // 75,776 B -> 2 blocks/CU
    __shared__ float red[NTHREADS / 64];

    const int tid = threadIdx.x;
    const int tx0 = blockIdx.x * TX;
    const int ty0 = blockIdx.y * TY;
    const long plane = (long)blockIdx.z * (H * W);
    const float* p1 = img1 + plane;
    const float* p2 = img2 + plane;

    const bool edge = (blockIdx.x == 0) || (blockIdx.x == GX - 1) ||
                      (blockIdx.y == 0) || (blockIdx.y == GY - 1);
    if (edge) phase1<true>(p1, p2, vb, tx0, ty0, wts, tid);
    else      phase1<false>(p1, p2, vb, tx0, ty0, wts, tid);

    __syncthreads();

    // Phase 2: horizontal 11-tap conv + SSIM map.
    // lane = row (stride 37 chunks, coprime with 32 banks -> conflict-free),
    // each thread handles 8 consecutive cols of one row.
    const int row = tid & 31;
    const int cg  = tid >> 5;            // 0..15
    const int c0  = cg * 8;

    float res[4][8];
    #pragma unroll
    for (int ch = 0; ch < 4; ++ch) {
        float f[20];
        #pragma unroll
        for (int j = 0; j < 5; ++j) {
            const float4 v = *(const float4*)&vb[ch][row][c0 + 4 * j];
            f[4 * j + 0] = v.x; f[4 * j + 1] = v.y;
            f[4 * j + 2] = v.z; f[4 * j + 3] = v.w;
        }
        #pragma unroll
        for (int j = 0; j < 8; ++j) {
            float s = wts.w[0] * f[j];
            #pragma unroll
            for (int k = 1; k < 11; ++k) s = fmaf(wts.w[k], f[j + k], s);
            res[ch][j] = s;
        }
    }

    float local = 0.f;
    #pragma unroll
    for (int j = 0; j < 8; ++j) {
        const float A  = res[0][j], Bv = res[1][j];
        const float Qa = res[2][j], Qb = res[3][j];
        const float u = A * A, v = Bv * Bv;
        const float t1 = u - v;                    // 4*mu1mu2
        const float t2 = u + v;                    // 2*(mu1^2+mu2^2)
        const float num1 = fmaf(0.5f, t1, C1);     // 2*mu1mu2 + C1
        const float den1 = fmaf(0.5f, t2, C1);     // mu1^2+mu2^2 + C1
        const float num2 = fmaf(0.5f, (Qa - Qb) - t1, C2);  // 2*sigma12 + C2
        const float den2 = fmaf(0.5f, (Qa + Qb) - t2, C2);  // sig1+sig2 + C2
        const float num = num1 * num2;
        const float den = den1 * den2;
        local += num * __builtin_amdgcn_rcpf(den);
    }

    // Block reduction: wave shuffle -> LDS -> one float partial per block.
    #pragma unroll
    for (int off = 32; off > 0; off >>= 1) local += __shfl_down(local, off, 64);
    if ((tid & 63) == 0) red[tid >> 6] = local;
    __syncthreads();
    if (tid == 0) {
        float s = 0.f;
        #pragma unroll
        for (int wv = 0; wv < NTHREADS / 64; ++wv) s += red[wv];
        const int bid = (blockIdx.z * GY + blockIdx.y) * GX + blockIdx.x;
        part[bid] = s;
    }
}

__global__ __launch_bounds__(512)
void ssim_final_kernel(const float* __restrict__ part, float* __restrict__ out)
{
    __shared__ double red[8];
    const int tid = threadIdx.x;
    double s = 0.0;
    for (int i = tid; i < NB; i += 512) s += (double)part[i];
    #pragma unroll
    for (int off = 32; off > 0; off >>= 1) s += __shfl_down(s, off, 64);
    if ((tid & 63) == 0) red[tid >> 6] = s;
    __syncthreads();
    if (tid == 0) {
        double t = 0.0;
        #pragma unroll
        for (int wv = 0; wv < 8; ++wv) t += red[wv];
        out[0] = (float)(1.0 - t / NTOT);
    }
}

extern "C" void kernel_launch(void* const* d_in, const int* in_sizes, int n_in,
                              void* d_out, int out_size, void* d_ws, size_t ws_size,
                              hipStream_t stream)
{
    const float* img1 = (const float*)d_in[0];
    const float* img2 = (const float*)d_in[1];
    float* out = (float*)d_out;
    float* part = (float*)d_ws;          // NB floats; fully rewritten each call

    Wts wts;
    double wd[11], s = 0.0;
    for (int k = 0; k < 11; ++k) {
        const double d = (double)(k - 5);
        wd[k] = exp(-0.5 / (1.5 * 1.5) * d * d);
        s += wd[k];
    }
    for (int k = 0; k < 11; ++k) wts.w[k] = (float)(wd[k] / s);

    dim3 grid(GX, GY, NPLANES);
    ssim_main_kernel<<<grid, NTHREADS, 0, stream>>>(img1, img2, part, wts);
    ssim_final_kernel<<<1, 512, 0, stream>>>(part, out);
}